// Round 3
// baseline (344.210 us; speedup 1.0000x reference)
//
#include <hip/hip_runtime.h>

// Problem constants
#define BB   16
#define CC   16
#define HH   256
#define WW   256
#define HID  128
#define OUTC 13

typedef short short8 __attribute__((ext_vector_type(8)));
typedef float floatx16 __attribute__((ext_vector_type(16)));
typedef float floatx4 __attribute__((ext_vector_type(4)));

// ---- helpers ----
__device__ __forceinline__ unsigned short f2bf(float x) {
    unsigned int u = __float_as_uint(x);
    u += 0x7fffu + ((u >> 16) & 1u);          // round-to-nearest-even
    return (unsigned short)(u >> 16);
}

// packed f32x2 -> bf16x2 (RNE), 1 instr instead of ~7
__device__ __forceinline__ unsigned int cvt_pk_bf16(float lo, float hi) {
    unsigned int d;
    asm("v_cvt_pk_bf16_f32 %0, %1, %2" : "=v"(d) : "v"(lo), "v"(hi));
    return d;
}

// ws layout: W1F frags [mtG 0..3][tap 0..8][lane 0..63][8 bf16]  = 36864 B
//            W2F frags [s 0..7][lane 0..63][8 bf16]              =  8192 B at +36864
#define W1F_BYTES 36864
#define W2F_OFF   36864

// ================= prep kernel: bake bf16 weight fragments ==================
__global__ __launch_bounds__(256) void gca_prep(
    const float* __restrict__ w1, const float* __restrict__ w2,
    unsigned char* __restrict__ ws)
{
    const int id = blockIdx.x * 256 + threadIdx.x;   // 2816 total
    const float SX[9] = {-1.f, 0.f, 1.f, -2.f, 0.f, 2.f, -1.f, 0.f, 1.f};
    const float SY[9] = {-1.f, -2.f, -1.f, 0.f, 0.f, 0.f, 1.f, 2.f, 1.f};

    if (id < 2304) {                                  // W1eff frags
        const int mtG  = id / 576;
        const int rem  = id % 576;
        const int tap  = rem / 64;
        const int lane = rem % 64;
        const int p  = lane & 31, hi = lane >> 5;
        const int hid = 32 * mtG + p;
        const float cen = (tap == 4) ? 1.f : 0.f;
        const float sxv = SX[tap], syv = SY[tap];
        const float* wr = w1 + hid * 48;
        unsigned int o[4];
        for (int k = 0; k < 4; ++k) {
            int c0 = 8 * hi + 2 * k;
            float v0 = wr[c0]     * cen + wr[16 + c0]     * sxv + wr[32 + c0]     * syv;
            float v1 = wr[c0 + 1] * cen + wr[16 + c0 + 1] * sxv + wr[32 + c0 + 1] * syv;
            o[k] = (unsigned int)f2bf(v0) | ((unsigned int)f2bf(v1) << 16);
        }
        *(uint4*)(ws + (size_t)id * 16) = make_uint4(o[0], o[1], o[2], o[3]);
    } else if (id < 2816) {                           // W2 (padded outc 13->32) frags
        const int id2 = id - 2304;
        const int s    = id2 / 64;
        const int lane = id2 % 64;
        const int outc = lane & 31, hi = lane >> 5;
        unsigned int o[4];
        for (int k = 0; k < 4; ++k) {
            int hid0 = 16 * s + 8 * hi + 2 * k;
            float v0 = (outc < OUTC) ? w2[outc * HID + hid0]     : 0.f;
            float v1 = (outc < OUTC) ? w2[outc * HID + hid0 + 1] : 0.f;
            o[k] = (unsigned int)f2bf(v0) | ((unsigned int)f2bf(v1) << 16);
        }
        *(uint4*)(ws + W2F_OFF + (size_t)id2 * 16) = make_uint4(o[0], o[1], o[2], o[3]);
    }
}

// ================= main kernel ==============================================
// Block = 256 thr = 4 waves = 2 pairs. Pair P handles pixel-row y0+2t+P each of
// 8 iterations. Wave hw in {0,1} owns hidden units 64*hw..64*hw+63 AND owns
// output channels of parity hw (parity split: outc&1 == r&1, hi-independent).
// LDS: bf16 input tile [18 rows][34 cols][16 c], 40B pixel stride (6120 dw)
//      + ping-pong partial-exchange buffers 2 x 1024 dw (4 sections x 256 dw).
// NOTE: plain stores only — nontemporal stores measured 3x WRITE_SIZE and
//       ~5x FETCH_SIZE amplification on gfx950 (round-2 counters).
#define TILE_DW 6120
#define CB_DW   1024
#define LDS_DW  (TILE_DW + 2 * CB_DW)    // 8168 dw = 32672 B -> 4 blocks/CU

__global__ __launch_bounds__(256, 4) void gca_main(
    const float* __restrict__ in,
    const float* __restrict__ b1,
    const unsigned char* __restrict__ ws,
    float* __restrict__ out)
{
    __shared__ unsigned int lds[LDS_DW];

    const int tid  = threadIdx.x;
    const int wid  = tid >> 6;
    const int lane = tid & 63;
    const int hw   = wid & 1;      // hid-half AND output-channel parity
    const int P    = wid >> 1;     // pair id
    const int p    = lane & 31;    // pixel-in-group / m-index
    const int hi   = lane >> 5;    // k-half selector

    const int bI = blockIdx.x >> 7;          // image
    const int rm = blockIdx.x & 127;
    const int y0 = (rm >> 3) << 4;           // 16-row span
    const int x0 = (rm & 7)  << 5;           // 32-px span

    const float* inb  = in  + ((size_t)bI << 20);
    float*       outb = out + ((size_t)bI << 20);

    // ---- prologue: passthrough channels 0..2 as 16B copy (plain stores) ----
    {
        int e = tid;
#pragma unroll
        for (int it = 0; it < 2; ++it) {
            if (e < 384) {
                int c = e >> 7, rem = e & 127, rw = rem >> 3, q = rem & 7;
                int idx = (c << 16) + ((y0 + rw) << 8) + x0 + (q << 2);
                *(floatx4*)(outb + idx) = *(const floatx4*)(inb + idx);
            }
            e += 256;
        }
    }

    // ---- stage halo tile (rows y0-1..y0+16, cols x0-1..x0+32), f32 -> bf16 ----
    // group g = channel pair (2g, 2g+1); lane l = column. No div/mod, packed cvt.
    {
        const int g = tid >> 5, l = tid & 31;
        const float* cp = inb + ((size_t)(2 * g) << 16);
        const int xA = (x0 + l - 1) & 255;
        const int xB = (x0 + l + 31) & 255;      // cols 32,33 (l<2 only)
        const int ldsA = l * 10 + g;
        const int ldsB = (l + 32) * 10 + g;
        const bool doB = (l < 2);
        for (int rw = 0; rw < 18; ++rw) {
            const int yo = ((y0 + rw - 1) & 255) << 8;
            float a0 = cp[yo + xA], a1 = cp[yo + xA + 65536];
            lds[rw * 340 + ldsA] = cvt_pk_bf16(a0, a1);
            if (doB) {
                float c0 = cp[yo + xB], c1 = cp[yo + xB + 65536];
                lds[rw * 340 + ldsB] = cvt_pk_bf16(c0, c1);
            }
        }
    }
    __syncthreads();

    const unsigned char* w1f  = ws + ((size_t)(2 * hw) * 9) * 64 * 16; // mtG base = 2*hw
    const unsigned char* w2fp = ws + W2F_OFF + (size_t)(4 * hw) * 64 * 16;

    // hoist W2 frags (t-invariant, 16 VGPRs)
    short8 a2f[4];
#pragma unroll
    for (int sp = 0; sp < 4; ++sp)
        a2f[sp] = *(const short8*)(w2fp + (size_t)(sp * 64 + lane) * 16);

    // hoisted epilogue constants: own-parity rows r = 2j+hw, outc mapping
    int off_[4]; bool val_[4];
#pragma unroll
    for (int j = 0; j < 4; ++j) {
        int r  = 2 * j + hw;
        int oc = (r & 3) + 8 * (r >> 2) + 4 * hi;
        val_[j] = (oc < OUTC);
        off_[j] = (3 + oc) << 16;
    }

    const int mysec = TILE_DW + (P * 2 + hw)       * 256 + 2 * lane;
    const int pasec = TILE_DW + (P * 2 + (1 - hw)) * 256 + 2 * lane;

#pragma unroll 1
    for (int t = 0; t < 8; ++t) {
        const int row   = y0 + 2 * t + P;
        const int ibase = (row << 8) + x0 + p;

        // ---- residual preload (own-parity channels) — hides under GEMM1 ----
        float rs[4];
#pragma unroll
        for (int j = 0; j < 4; ++j)
            rs[j] = val_[j] ? inb[ibase + off_[j]] : 0.f;

        // ---- acc1 init = b1 (pre-relu bias) ----
        floatx16 acc1[2];
#pragma unroll
        for (int m = 0; m < 2; ++m) {
            const int hb = 64 * hw + 32 * m + 4 * hi;
#pragma unroll
            for (int rr = 0; rr < 4; ++rr) {
                float4 bv = *(const float4*)(b1 + hb + 8 * rr);
                acc1[m][4 * rr + 0] = bv.x;
                acc1[m][4 * rr + 1] = bv.y;
                acc1[m][4 * rr + 2] = bv.z;
                acc1[m][4 * rr + 3] = bv.w;
            }
        }

        // ---- GEMM1: 9 taps (K=16 each), A = W1eff frags, B = bf16 pixel tile ----
#pragma unroll
        for (int tap = 0; tap < 9; ++tap) {
            const int tr  = 2 * t + P + tap / 3;
            const int col = p + tap % 3;
            const int dwo = (tr * 34 + col) * 10 + 4 * hi;
            union { unsigned int u[4]; short8 s; } bfr;
            uint2 lo2 = *(const uint2*)&lds[dwo];
            uint2 hi2 = *(const uint2*)&lds[dwo + 2];
            bfr.u[0] = lo2.x; bfr.u[1] = lo2.y; bfr.u[2] = hi2.x; bfr.u[3] = hi2.y;
#pragma unroll
            for (int m = 0; m < 2; ++m) {
                short8 af = *(const short8*)(w1f + (size_t)((m * 9 + tap) * 64 + lane) * 16);
                acc1[m] = __builtin_amdgcn_mfma_f32_32x32x16_bf16(af, bfr.s, acc1[m], 0, 0, 0);
            }
        }

        // ---- relu + pack h (packed cvt) ----
        uint2 hrun[8];
#pragma unroll
        for (int m = 0; m < 2; ++m)
#pragma unroll
            for (int rr = 0; rr < 4; ++rr) {
                float h0 = fmaxf(acc1[m][4 * rr + 0], 0.f);
                float h1 = fmaxf(acc1[m][4 * rr + 1], 0.f);
                float h2 = fmaxf(acc1[m][4 * rr + 2], 0.f);
                float h3 = fmaxf(acc1[m][4 * rr + 3], 0.f);
                hrun[4 * m + rr].x = cvt_pk_bf16(h0, h1);
                hrun[4 * m + rr].y = cvt_pk_bf16(h2, h3);
            }

        // ---- acc2 C-init = residual on own-parity rows (static idx per branch) ----
        floatx16 acc2 = {};
        if (hw == 0) { acc2[0] = rs[0]; acc2[2] = rs[1]; acc2[4] = rs[2]; acc2[6] = rs[3]; }
        else         { acc2[1] = rs[0]; acc2[3] = rs[1]; acc2[5] = rs[2]; acc2[7] = rs[3]; }

        // ---- GEMM2 (partial over this wave's 64 hids): D[outc32][pixel32] ----
#pragma unroll
        for (int sp = 0; sp < 4; ++sp) {
            uint2 r0 = hrun[2 * sp];
            uint2 r1 = hrun[2 * sp + 1];
            uint2 x0s, x1s;
            x0s.x = (unsigned int)__shfl_xor((int)r0.x, 32);
            x0s.y = (unsigned int)__shfl_xor((int)r0.y, 32);
            x1s.x = (unsigned int)__shfl_xor((int)r1.x, 32);
            x1s.y = (unsigned int)__shfl_xor((int)r1.y, 32);
            union { unsigned int u[4]; short8 s; } b2;
            uint2 lo = hi ? x1s : r0;
            uint2 hg = hi ? r1  : x0s;
            b2.u[0] = lo.x; b2.u[1] = lo.y; b2.u[2] = hg.x; b2.u[3] = hg.y;
            acc2 = __builtin_amdgcn_mfma_f32_32x32x16_bf16(a2f[sp], b2.s, acc2, 0, 0, 0);
        }

        // ---- write opposite-parity partial rows for partner (2 x b64) ----
        const int cb = mysec + (t & 1) * CB_DW;
        uint2 wv0, wv1;
        if (hw == 0) {
            wv0.x = __float_as_uint(acc2[1]); wv0.y = __float_as_uint(acc2[3]);
            wv1.x = __float_as_uint(acc2[5]); wv1.y = __float_as_uint(acc2[7]);
        } else {
            wv0.x = __float_as_uint(acc2[0]); wv0.y = __float_as_uint(acc2[2]);
            wv1.x = __float_as_uint(acc2[4]); wv1.y = __float_as_uint(acc2[6]);
        }
        *(uint2*)&lds[cb]       = wv0;
        *(uint2*)&lds[cb + 128] = wv1;

        __syncthreads();   // single barrier/iter; ping-pong protects cross-iter reuse

        // ---- read partner partials, finish own-parity channels, store ----
        const int pb = pasec + (t & 1) * CB_DW;
        uint2 q0 = *(const uint2*)&lds[pb];
        uint2 q1 = *(const uint2*)&lds[pb + 128];

        float s_[4];
        if (hw == 0) {
            s_[0] = acc2[0] + __uint_as_float(q0.x);
            s_[1] = acc2[2] + __uint_as_float(q0.y);
            s_[2] = acc2[4] + __uint_as_float(q1.x);
            s_[3] = acc2[6] + __uint_as_float(q1.y);
        } else {
            s_[0] = acc2[1] + __uint_as_float(q0.x);
            s_[1] = acc2[3] + __uint_as_float(q0.y);
            s_[2] = acc2[5] + __uint_as_float(q1.x);
            s_[3] = acc2[7] + __uint_as_float(q1.y);
        }
#pragma unroll
        for (int j = 0; j < 4; ++j)
            if (val_[j])
                outb[ibase + off_[j]] = s_[j];
    }
}

extern "C" void kernel_launch(void* const* d_in, const int* in_sizes, int n_in,
                              void* d_out, int out_size, void* d_ws, size_t ws_size,
                              hipStream_t stream) {
    const float* x  = (const float*)d_in[0];
    const float* w1 = (const float*)d_in[1];
    const float* b1 = (const float*)d_in[2];
    const float* w2 = (const float*)d_in[3];
    float* out = (float*)d_out;
    unsigned char* ws = (unsigned char*)d_ws;

    hipLaunchKernelGGL(gca_prep, dim3(11), dim3(256), 0, stream, w1, w2, ws);
    hipLaunchKernelGGL(gca_main, dim3(2048), dim3(256), 0, stream, x, b1, ws, out);
}

// Round 4
// 250.188 us; speedup vs baseline: 1.3758x; 1.3758x over previous
//
#include <hip/hip_runtime.h>

// Problem constants
#define BB   16
#define CC   16
#define HH   256
#define WW   256
#define HID  128
#define OUTC 13

typedef short short8 __attribute__((ext_vector_type(8)));
typedef float floatx16 __attribute__((ext_vector_type(16)));
typedef float floatx4 __attribute__((ext_vector_type(4)));

// ---- helpers ----
__device__ __forceinline__ unsigned short f2bf(float x) {
    unsigned int u = __float_as_uint(x);
    u += 0x7fffu + ((u >> 16) & 1u);          // round-to-nearest-even
    return (unsigned short)(u >> 16);
}

// packed f32x2 -> bf16x2 (RNE), 1 instr instead of ~7
__device__ __forceinline__ unsigned int cvt_pk_bf16(float lo, float hi) {
    unsigned int d;
    asm("v_cvt_pk_bf16_f32 %0, %1, %2" : "=v"(d) : "v"(lo), "v"(hi));
    return d;
}

// ws layout: W1F frags [mtG 0..3][tap 0..8][lane 0..63][8 bf16]  = 36864 B
//            W2F frags [s 0..7][lane 0..63][8 bf16]              =  8192 B at +36864
#define W1F_BYTES 36864
#define W2F_OFF   36864

// ================= prep kernel: bake bf16 weight fragments ==================
__global__ __launch_bounds__(256) void gca_prep(
    const float* __restrict__ w1, const float* __restrict__ w2,
    unsigned char* __restrict__ ws)
{
    const int id = blockIdx.x * 256 + threadIdx.x;   // 2816 total
    const float SX[9] = {-1.f, 0.f, 1.f, -2.f, 0.f, 2.f, -1.f, 0.f, 1.f};
    const float SY[9] = {-1.f, -2.f, -1.f, 0.f, 0.f, 0.f, 1.f, 2.f, 1.f};

    if (id < 2304) {                                  // W1eff frags
        const int mtG  = id / 576;
        const int rem  = id % 576;
        const int tap  = rem / 64;
        const int lane = rem % 64;
        const int p  = lane & 31, hi = lane >> 5;
        const int hid = 32 * mtG + p;
        const float cen = (tap == 4) ? 1.f : 0.f;
        const float sxv = SX[tap], syv = SY[tap];
        const float* wr = w1 + hid * 48;
        unsigned int o[4];
        for (int k = 0; k < 4; ++k) {
            int c0 = 8 * hi + 2 * k;
            float v0 = wr[c0]     * cen + wr[16 + c0]     * sxv + wr[32 + c0]     * syv;
            float v1 = wr[c0 + 1] * cen + wr[16 + c0 + 1] * sxv + wr[32 + c0 + 1] * syv;
            o[k] = (unsigned int)f2bf(v0) | ((unsigned int)f2bf(v1) << 16);
        }
        *(uint4*)(ws + (size_t)id * 16) = make_uint4(o[0], o[1], o[2], o[3]);
    } else if (id < 2816) {                           // W2 (padded outc 13->32) frags
        const int id2 = id - 2304;
        const int s    = id2 / 64;
        const int lane = id2 % 64;
        const int outc = lane & 31, hi = lane >> 5;
        unsigned int o[4];
        for (int k = 0; k < 4; ++k) {
            int hid0 = 16 * s + 8 * hi + 2 * k;
            float v0 = (outc < OUTC) ? w2[outc * HID + hid0]     : 0.f;
            float v1 = (outc < OUTC) ? w2[outc * HID + hid0 + 1] : 0.f;
            o[k] = (unsigned int)f2bf(v0) | ((unsigned int)f2bf(v1) << 16);
        }
        *(uint4*)(ws + W2F_OFF + (size_t)id2 * 16) = make_uint4(o[0], o[1], o[2], o[3]);
    }
}

// ================= main kernel ==============================================
// Block = 256 thr = 4 waves = 2 pairs. Pair P handles pixel-row y0+2t+P each of
// 8 iterations. Wave hw in {0,1} owns hidden units 64*hw..64*hw+63 AND owns
// output channels of parity hw (parity split: outc&1 == r&1, hi-independent).
// LDS: bf16 input tile [18 rows][34 cols][16 c], 40B pixel stride (6120 dw)
//      + ping-pong partial-exchange buffers 2 x 1024 dw (4 sections x 256 dw).
// NOTES (measured, rounds 2-3):
//  - NO __launch_bounds__ occupancy clause: (256,4) capped the unified
//    VGPR+AGPR file at ~128 regs/thread -> scratch spills -> FETCH 120->670 MB,
//    WRITE 64->205 MB, 2x slowdown. Live set here is ~150 regs.
//  - plain stores (nontemporal made no measurable difference; untangled from
//    the spill regression it was never retested -> keep plain).
#define TILE_DW 6120
#define CB_DW   1024
#define LDS_DW  (TILE_DW + 2 * CB_DW)    // 8168 dw = 32672 B -> 4 blocks/CU by LDS

__global__ __launch_bounds__(256) void gca_main(
    const float* __restrict__ in,
    const float* __restrict__ b1,
    const unsigned char* __restrict__ ws,
    float* __restrict__ out)
{
    __shared__ unsigned int lds[LDS_DW];

    const int tid  = threadIdx.x;
    const int wid  = tid >> 6;
    const int lane = tid & 63;
    const int hw   = wid & 1;      // hid-half AND output-channel parity
    const int P    = wid >> 1;     // pair id
    const int p    = lane & 31;    // pixel-in-group / m-index
    const int hi   = lane >> 5;    // k-half selector

    const int bI = blockIdx.x >> 7;          // image
    const int rm = blockIdx.x & 127;
    const int y0 = (rm >> 3) << 4;           // 16-row span
    const int x0 = (rm & 7)  << 5;           // 32-px span

    const float* inb  = in  + ((size_t)bI << 20);
    float*       outb = out + ((size_t)bI << 20);

    // ---- prologue: passthrough channels 0..2 as 16B copy (plain stores) ----
    {
        int e = tid;
#pragma unroll
        for (int it = 0; it < 2; ++it) {
            if (e < 384) {
                int c = e >> 7, rem = e & 127, rw = rem >> 3, q = rem & 7;
                int idx = (c << 16) + ((y0 + rw) << 8) + x0 + (q << 2);
                *(floatx4*)(outb + idx) = *(const floatx4*)(inb + idx);
            }
            e += 256;
        }
    }

    // ---- stage halo tile (rows y0-1..y0+16, cols x0-1..x0+32), f32 -> bf16 ----
    // group g = channel pair (2g, 2g+1); lane l = column. No div/mod, packed cvt.
    {
        const int g = tid >> 5, l = tid & 31;
        const float* cp = inb + ((size_t)(2 * g) << 16);
        const int xA = (x0 + l - 1) & 255;
        const int xB = (x0 + l + 31) & 255;      // cols 32,33 (l<2 only)
        const int ldsA = l * 10 + g;
        const int ldsB = (l + 32) * 10 + g;
        const bool doB = (l < 2);
        for (int rw = 0; rw < 18; ++rw) {
            const int yo = ((y0 + rw - 1) & 255) << 8;
            float a0 = cp[yo + xA], a1 = cp[yo + xA + 65536];
            lds[rw * 340 + ldsA] = cvt_pk_bf16(a0, a1);
            if (doB) {
                float c0 = cp[yo + xB], c1 = cp[yo + xB + 65536];
                lds[rw * 340 + ldsB] = cvt_pk_bf16(c0, c1);
            }
        }
    }
    __syncthreads();

    const unsigned char* w1f  = ws + ((size_t)(2 * hw) * 9) * 64 * 16; // mtG base = 2*hw
    const unsigned char* w2fp = ws + W2F_OFF + (size_t)(4 * hw) * 64 * 16;

    // hoist W2 frags (t-invariant, 16 VGPRs)
    short8 a2f[4];
#pragma unroll
    for (int sp = 0; sp < 4; ++sp)
        a2f[sp] = *(const short8*)(w2fp + (size_t)(sp * 64 + lane) * 16);

    // hoisted epilogue constants: own-parity rows r = 2j+hw, outc mapping
    int off_[4]; bool val_[4];
#pragma unroll
    for (int j = 0; j < 4; ++j) {
        int r  = 2 * j + hw;
        int oc = (r & 3) + 8 * (r >> 2) + 4 * hi;
        val_[j] = (oc < OUTC);
        off_[j] = (3 + oc) << 16;
    }

    const int mysec = TILE_DW + (P * 2 + hw)       * 256 + 2 * lane;
    const int pasec = TILE_DW + (P * 2 + (1 - hw)) * 256 + 2 * lane;

#pragma unroll 1
    for (int t = 0; t < 8; ++t) {
        const int row   = y0 + 2 * t + P;
        const int ibase = (row << 8) + x0 + p;

        // ---- residual preload (own-parity channels) — hides under GEMM1 ----
        float rs[4];
#pragma unroll
        for (int j = 0; j < 4; ++j)
            rs[j] = val_[j] ? inb[ibase + off_[j]] : 0.f;

        // ---- acc1 init = b1 (pre-relu bias) ----
        floatx16 acc1[2];
#pragma unroll
        for (int m = 0; m < 2; ++m) {
            const int hb = 64 * hw + 32 * m + 4 * hi;
#pragma unroll
            for (int rr = 0; rr < 4; ++rr) {
                float4 bv = *(const float4*)(b1 + hb + 8 * rr);
                acc1[m][4 * rr + 0] = bv.x;
                acc1[m][4 * rr + 1] = bv.y;
                acc1[m][4 * rr + 2] = bv.z;
                acc1[m][4 * rr + 3] = bv.w;
            }
        }

        // ---- GEMM1: 9 taps (K=16 each), A = W1eff frags, B = bf16 pixel tile ----
#pragma unroll
        for (int tap = 0; tap < 9; ++tap) {
            const int tr  = 2 * t + P + tap / 3;
            const int col = p + tap % 3;
            const int dwo = (tr * 34 + col) * 10 + 4 * hi;
            union { unsigned int u[4]; short8 s; } bfr;
            uint2 lo2 = *(const uint2*)&lds[dwo];
            uint2 hi2 = *(const uint2*)&lds[dwo + 2];
            bfr.u[0] = lo2.x; bfr.u[1] = lo2.y; bfr.u[2] = hi2.x; bfr.u[3] = hi2.y;
#pragma unroll
            for (int m = 0; m < 2; ++m) {
                short8 af = *(const short8*)(w1f + (size_t)((m * 9 + tap) * 64 + lane) * 16);
                acc1[m] = __builtin_amdgcn_mfma_f32_32x32x16_bf16(af, bfr.s, acc1[m], 0, 0, 0);
            }
        }

        // ---- relu + pack h (packed cvt) ----
        uint2 hrun[8];
#pragma unroll
        for (int m = 0; m < 2; ++m)
#pragma unroll
            for (int rr = 0; rr < 4; ++rr) {
                float h0 = fmaxf(acc1[m][4 * rr + 0], 0.f);
                float h1 = fmaxf(acc1[m][4 * rr + 1], 0.f);
                float h2 = fmaxf(acc1[m][4 * rr + 2], 0.f);
                float h3 = fmaxf(acc1[m][4 * rr + 3], 0.f);
                hrun[4 * m + rr].x = cvt_pk_bf16(h0, h1);
                hrun[4 * m + rr].y = cvt_pk_bf16(h2, h3);
            }

        // ---- acc2 C-init = residual on own-parity rows (static idx per branch) ----
        floatx16 acc2 = {};
        if (hw == 0) { acc2[0] = rs[0]; acc2[2] = rs[1]; acc2[4] = rs[2]; acc2[6] = rs[3]; }
        else         { acc2[1] = rs[0]; acc2[3] = rs[1]; acc2[5] = rs[2]; acc2[7] = rs[3]; }

        // ---- GEMM2 (partial over this wave's 64 hids): D[outc32][pixel32] ----
#pragma unroll
        for (int sp = 0; sp < 4; ++sp) {
            uint2 r0 = hrun[2 * sp];
            uint2 r1 = hrun[2 * sp + 1];
            uint2 x0s, x1s;
            x0s.x = (unsigned int)__shfl_xor((int)r0.x, 32);
            x0s.y = (unsigned int)__shfl_xor((int)r0.y, 32);
            x1s.x = (unsigned int)__shfl_xor((int)r1.x, 32);
            x1s.y = (unsigned int)__shfl_xor((int)r1.y, 32);
            union { unsigned int u[4]; short8 s; } b2;
            uint2 lo = hi ? x1s : r0;
            uint2 hg = hi ? r1  : x0s;
            b2.u[0] = lo.x; b2.u[1] = lo.y; b2.u[2] = hg.x; b2.u[3] = hg.y;
            acc2 = __builtin_amdgcn_mfma_f32_32x32x16_bf16(a2f[sp], b2.s, acc2, 0, 0, 0);
        }

        // ---- write opposite-parity partial rows for partner (2 x b64) ----
        const int cb = mysec + (t & 1) * CB_DW;
        uint2 wv0, wv1;
        if (hw == 0) {
            wv0.x = __float_as_uint(acc2[1]); wv0.y = __float_as_uint(acc2[3]);
            wv1.x = __float_as_uint(acc2[5]); wv1.y = __float_as_uint(acc2[7]);
        } else {
            wv0.x = __float_as_uint(acc2[0]); wv0.y = __float_as_uint(acc2[2]);
            wv1.x = __float_as_uint(acc2[4]); wv1.y = __float_as_uint(acc2[6]);
        }
        *(uint2*)&lds[cb]       = wv0;
        *(uint2*)&lds[cb + 128] = wv1;

        __syncthreads();   // single barrier/iter; ping-pong protects cross-iter reuse

        // ---- read partner partials, finish own-parity channels, store ----
        const int pb = pasec + (t & 1) * CB_DW;
        uint2 q0 = *(const uint2*)&lds[pb];
        uint2 q1 = *(const uint2*)&lds[pb + 128];

        float s_[4];
        if (hw == 0) {
            s_[0] = acc2[0] + __uint_as_float(q0.x);
            s_[1] = acc2[2] + __uint_as_float(q0.y);
            s_[2] = acc2[4] + __uint_as_float(q1.x);
            s_[3] = acc2[6] + __uint_as_float(q1.y);
        } else {
            s_[0] = acc2[1] + __uint_as_float(q0.x);
            s_[1] = acc2[3] + __uint_as_float(q0.y);
            s_[2] = acc2[5] + __uint_as_float(q1.x);
            s_[3] = acc2[7] + __uint_as_float(q1.y);
        }
#pragma unroll
        for (int j = 0; j < 4; ++j)
            if (val_[j])
                outb[ibase + off_[j]] = s_[j];
    }
}

extern "C" void kernel_launch(void* const* d_in, const int* in_sizes, int n_in,
                              void* d_out, int out_size, void* d_ws, size_t ws_size,
                              hipStream_t stream) {
    const float* x  = (const float*)d_in[0];
    const float* w1 = (const float*)d_in[1];
    const float* b1 = (const float*)d_in[2];
    const float* w2 = (const float*)d_in[3];
    float* out = (float*)d_out;
    unsigned char* ws = (unsigned char*)d_ws;

    hipLaunchKernelGGL(gca_prep, dim3(11), dim3(256), 0, stream, w1, w2, ws);
    hipLaunchKernelGGL(gca_main, dim3(2048), dim3(256), 0, stream, x, b1, ws, out);
}